// Round 7
// baseline (399.553 us; speedup 1.0000x reference)
//
#include <hip/hip_runtime.h>
#include <math.h>

typedef __attribute__((ext_vector_type(8))) short bf16x8;
typedef __attribute__((ext_vector_type(4))) float f32x4;

#define BSHIFT 7               // 128 nodes per bucket
#define CH 8192                // edges per block in bucket hist/scatter

__device__ inline unsigned short f32_to_bf16_bits(float f) {
    unsigned int u = __float_as_uint(f);
    unsigned int r = (u + 0x7fffu + ((u >> 16) & 1u)) >> 16;   // RNE
    return (unsigned short)r;
}
__device__ inline float bf16_bits_to_f32(unsigned short h) {
    return __uint_as_float(((unsigned int)h) << 16);
}

// single-instruction lane xor-swizzle add (BitMode: (xor<<10)|0x1F)
#define SWZ_ADD(t, imm) \
    t += __int_as_float(__builtin_amdgcn_ds_swizzle(__float_as_int(t), imm))

// ================= 2-level bucket CSR build =================

__global__ __launch_bounds__(256) void bucket_hist(
    const int* __restrict__ dst, int* __restrict__ bcnt8, int E, int nb, int nbp)
{
    __shared__ int h[1024];
    for (int i = threadIdx.x; i < nb; i += 256) h[i] = 0;
    __syncthreads();
    int e0 = blockIdx.x * CH, e1 = min(e0 + CH, E);
    for (int e = e0 + (int)threadIdx.x; e < e1; e += 256)
        atomicAdd(&h[dst[e] >> BSHIFT], 1);
    __syncthreads();
    int* mycnt = bcnt8 + (blockIdx.x & 7) * nbp;
    for (int b = threadIdx.x; b < nb; b += 256) {
        int c = h[b];
        if (c) atomicAdd(&mycnt[b], c);
    }
}

__global__ void bucket_scan(const int* __restrict__ bcnt8, int* __restrict__ bbase,
                            int* __restrict__ bcur8, int* __restrict__ rowstart,
                            int nb, int nbp, int E, int N)
{
    __shared__ int sh[1024];
    int t = threadIdx.x;
    int g8[8];
    int tot = 0;
#pragma unroll
    for (int g = 0; g < 8; ++g) {
        int c = (t < nb) ? bcnt8[g * nbp + t] : 0;
        g8[g] = c; tot += c;
    }
    sh[t] = tot;
    __syncthreads();
    for (int d = 1; d < 1024; d <<= 1) {
        int a = (t >= d) ? sh[t - d] : 0;
        __syncthreads();
        sh[t] += a;
        __syncthreads();
    }
    int base = sh[t] - tot;   // exclusive
    if (t <= nb) bbase[t] = base;
    if (t < nb) {
        int run = base;
#pragma unroll
        for (int g = 0; g < 8; ++g) { bcur8[g * nbp + t] = run; run += g8[g]; }
    }
    if (t == 0) rowstart[N] = E;
}

__global__ __launch_bounds__(256) void bucket_scatter(
    const int* __restrict__ src, const int* __restrict__ dst,
    int* __restrict__ bcur8, unsigned* __restrict__ pairs, int E, int nb, int nbp)
{
    __shared__ int h[1024];
    for (int i = threadIdx.x; i < nb; i += 256) h[i] = 0;
    __syncthreads();
    int e0 = blockIdx.x * CH, e1 = min(e0 + CH, E);
    for (int e = e0 + (int)threadIdx.x; e < e1; e += 256)
        atomicAdd(&h[dst[e] >> BSHIFT], 1);
    __syncthreads();
    int* mycur = bcur8 + (blockIdx.x & 7) * nbp;
    for (int b = threadIdx.x; b < nb; b += 256) {
        int c = h[b];
        if (c) h[b] = atomicAdd(&mycur[b], c);
    }
    __syncthreads();
    for (int e = e0 + (int)threadIdx.x; e < e1; e += 256) {
        int d = dst[e];
        int pos = atomicAdd(&h[d >> BSHIFT], 1);
        // pack: src (17 bits) << 7 | local dst (7 bits)
        pairs[pos] = ((unsigned)src[e] << BSHIFT) | (unsigned)(d & 127);
    }
}

__global__ __launch_bounds__(256) void bucket_finalize(
    const unsigned* __restrict__ pairs, const int* __restrict__ bbase,
    int* __restrict__ rowstart, int* __restrict__ csr_src, int N)
{
    __shared__ int h[128];
    __shared__ int sh[256];
    int b = blockIdx.x;
    int p0 = bbase[b], p1 = bbase[b + 1];
    int t = threadIdx.x;
    if (t < 128) h[t] = 0;
    __syncthreads();
    for (int e = p0 + t; e < p1; e += 256)
        atomicAdd(&h[pairs[e] & 127], 1);
    __syncthreads();
    int v = (t < 128) ? h[t] : 0;
    sh[t] = v;
    __syncthreads();
    for (int d = 1; d < 256; d <<= 1) {
        int a = (t >= d) ? sh[t - d] : 0;
        __syncthreads();
        sh[t] += a;
        __syncthreads();
    }
    if (t < 128) {
        int off = sh[t] - v;
        int node = (b << BSHIFT) + t;
        if (node < N) rowstart[node] = p0 + off;
        h[t] = p0 + off;
    }
    __syncthreads();
    for (int e = p0 + t; e < p1; e += 256) {
        unsigned pr = pairs[e];
        int pos = atomicAdd(&h[pr & 127], 1);
        csr_src[pos] = (int)(pr >> BSHIFT);
    }
}

// ================= weight prepack =================

__global__ void prepack_kernel(const float* __restrict__ Wl, const float* __restrict__ Wr,
                               unsigned short* __restrict__ pWl, unsigned short* __restrict__ pWr,
                               int FIN, int FOUT) {
    int NT = FOUT >> 4, NK = FIN >> 5;
    int part = NT * NK * 512;
    int i = blockIdx.x * blockDim.x + threadIdx.x;
    int m = i / part;
    if (m >= 2) return;
    int ii = i - m * part;
    int j = ii & 7;
    int lane = (ii >> 3) & 63;
    int rest = ii >> 9;
    int ks = rest % NK;
    int t = rest / NK;
    int k = ks * 32 + (lane >> 4) * 8 + j;
    int c = t * 16 + (lane & 15);
    const float* W = m ? Wr : Wl;
    unsigned short* P = m ? pWr : pWl;
    float w = W[(size_t)k * FOUT + c];
    unsigned short hi = f32_to_bf16_bits(w);
    unsigned short lo = f32_to_bf16_bits(w - bf16_bits_to_f32(hi));
    P[ii] = hi;
    P[part + ii] = lo;
}

// ================= MFMA projection + att-dot epilogue =================

template<int FIN, int FOUT>
__global__ __launch_bounds__(256) void proj_mfma_kernel(
    const float* __restrict__ x,
    const unsigned short* __restrict__ pWl, const unsigned short* __restrict__ pWr,
    const float* __restrict__ att,
    float* __restrict__ xl, float* __restrict__ xr,
    float* __restrict__ dl, float* __restrict__ dr, int n)
{
    constexpr int NT = FOUT >> 4;
    constexpr int NK = FIN >> 5;
    constexpr int PART = NT * NK * 512;
    const int wave = threadIdx.x >> 6;
    const int lane = threadIdx.x & 63;
    const int row0 = blockIdx.x * 64 + wave * 16;
    int arow = row0 + (lane & 15);
    if (arow >= n) arow = n - 1;
    const int khalf = lane >> 4;

    f32x4 accl[NT], accr[NT];
#pragma unroll
    for (int t = 0; t < NT; ++t) {
        accl[t] = (f32x4){0.f, 0.f, 0.f, 0.f};
        accr[t] = (f32x4){0.f, 0.f, 0.f, 0.f};
    }

    const float* xrow = x + (size_t)arow * FIN + khalf * 8;
#pragma unroll
    for (int ks = 0; ks < NK; ++ks) {
        float4 a0 = *(const float4*)(xrow + ks * 32);
        float4 a1 = *(const float4*)(xrow + ks * 32 + 4);
        float av[8] = {a0.x, a0.y, a0.z, a0.w, a1.x, a1.y, a1.z, a1.w};
        bf16x8 ah, al;
#pragma unroll
        for (int j = 0; j < 8; ++j) {
            unsigned short h = f32_to_bf16_bits(av[j]);
            ah[j] = (short)h;
            al[j] = (short)f32_to_bf16_bits(av[j] - bf16_bits_to_f32(h));
        }
#pragma unroll
        for (int t = 0; t < NT; ++t) {
            const unsigned short* bpl = pWl + ((size_t)(t * NK + ks) * 64 + lane) * 8;
            bf16x8 bh  = *(const bf16x8*)bpl;
            bf16x8 blo = *(const bf16x8*)(bpl + PART);
            accl[t] = __builtin_amdgcn_mfma_f32_16x16x32_bf16(ah, bh,  accl[t], 0, 0, 0);
            accl[t] = __builtin_amdgcn_mfma_f32_16x16x32_bf16(ah, blo, accl[t], 0, 0, 0);
            accl[t] = __builtin_amdgcn_mfma_f32_16x16x32_bf16(al, bh,  accl[t], 0, 0, 0);
            const unsigned short* bpr = pWr + ((size_t)(t * NK + ks) * 64 + lane) * 8;
            bh  = *(const bf16x8*)bpr;
            blo = *(const bf16x8*)(bpr + PART);
            accr[t] = __builtin_amdgcn_mfma_f32_16x16x32_bf16(ah, bh,  accr[t], 0, 0, 0);
            accr[t] = __builtin_amdgcn_mfma_f32_16x16x32_bf16(ah, blo, accr[t], 0, 0, 0);
            accr[t] = __builtin_amdgcn_mfma_f32_16x16x32_bf16(al, bh,  accr[t], 0, 0, 0);
        }
    }

    const int orow0 = row0 + khalf * 4;
    const int colb = lane & 15;
    float attc[NT];
#pragma unroll
    for (int t = 0; t < NT; ++t) attc[t] = att[t * 16 + colb];

#pragma unroll
    for (int t = 0; t < NT; ++t) {
        int col = t * 16 + colb;
#pragma unroll
        for (int r = 0; r < 4; ++r) {
            int rr = orow0 + r;
            if (rr < n) {
                xl[(size_t)rr * FOUT + col] = accl[t][r];
                xr[(size_t)rr * FOUT + col] = accr[t][r];
            }
        }
    }
#pragma unroll
    for (int r = 0; r < 4; ++r) {
        float pl = 0.f, pr = 0.f;
#pragma unroll
        for (int t = 0; t < NT; ++t) { pl += accl[t][r] * attc[t]; pr += accr[t][r] * attc[t]; }
#pragma unroll
        for (int off = 1; off < 16; off <<= 1) {
            pl += __shfl_xor(pl, off);
            pr += __shfl_xor(pr, off);
        }
        int rr = orow0 + r;
        if (colb == 0 && rr < n) { dl[rr] = pl; dr[rr] = pr; }
    }
}

// ================= per-dst online-softmax aggregation =================
// Group-per-node, 2-edge software pipeline: next pair's csr/dl/xl loads issue
// while current pair computes (2x MLP, full-iteration load->use distance).
// score = 0.6*(dl[src]+dr[dst]) + 0.4*sum(att*|s|); pair-merged defer-max.

template<int F, int AMODE>
__global__ __launch_bounds__(256) void agg_kernel(
    const float* __restrict__ xl, const float* __restrict__ xr, const float* __restrict__ att,
    const float* __restrict__ dl, const float* __restrict__ dr,
    const int* __restrict__ rowstart, const int* __restrict__ csr_src,
    float* __restrict__ out, int n, int E)
{
    constexpr int LPE = F / 4;            // lanes per node
    constexpr int LSH = (F == 64) ? 6 : 5;
    constexpr int NPG = 64 / LPE;         // nodes per wave

    int wv  = (blockIdx.x * blockDim.x + threadIdx.x) >> 6;
    int lane = threadIdx.x & 63;
    int grp = lane / LPE;
    int fl  = lane % LPE;
    int node = wv * NPG + grp;
    bool act = node < n;
    int nc = act ? node : 0;

    float4 xrv  = *(const float4*)&xr[((unsigned)nc << LSH) + fl * 4];
    float4 attv = *(const float4*)&att[fl * 4];
    float cdr = 0.6f * dr[nc];

    int s0 = rowstart[nc];
    int s1 = act ? rowstart[nc + 1] : s0;
    int Ec = E - 1;

    float m = -1e30f, mth = -1e30f, ssum = 0.f;
    float o0 = 0.f, o1 = 0.f, o2 = 0.f, o3 = 0.f;

    // pipeline preload for edge pair (ia, ib)
    int ia = s0, ib = s0 + 1;
    int sva = csr_src[min(ia, Ec)];
    int svb = csr_src[min(ib, Ec)];
    float dla = dl[sva], dlb = dl[svb];
    float4 xa = *(const float4*)(xl + (((unsigned)sva << LSH) + fl * 4));
    float4 xb = *(const float4*)(xl + (((unsigned)svb << LSH) + fl * 4));

    while (ia < s1) {
        // prefetch next pair (used next iteration)
        int nia = ia + 2, nib = ib + 2;
        int nsva = csr_src[min(nia, Ec)];
        int nsvb = csr_src[min(nib, Ec)];
        float ndla = dl[nsva], ndlb = dl[nsvb];
        float4 nxa = *(const float4*)(xl + (((unsigned)nsva << LSH) + fl * 4));
        float4 nxb = *(const float4*)(xl + (((unsigned)nsvb << LSH) + fl * 4));

        bool vb = ib < s1;
        float ta = attv.x * fabsf(xa.x + xrv.x)
                 + attv.y * fabsf(xa.y + xrv.y)
                 + attv.z * fabsf(xa.z + xrv.z)
                 + attv.w * fabsf(xa.w + xrv.w);
        float tb = attv.x * fabsf(xb.x + xrv.x)
                 + attv.y * fabsf(xb.y + xrv.y)
                 + attv.z * fabsf(xb.z + xrv.z)
                 + attv.w * fabsf(xb.w + xrv.w);
        SWZ_ADD(ta, 0x041F); SWZ_ADD(tb, 0x041F);   // xor 1
        SWZ_ADD(ta, 0x081F); SWZ_ADD(tb, 0x081F);   // xor 2
        SWZ_ADD(ta, 0x101F); SWZ_ADD(tb, 0x101F);   // xor 4
        if (LPE == 16) { SWZ_ADD(ta, 0x201F); SWZ_ADD(tb, 0x201F); }  // xor 8

        float pa = 0.6f * dla + cdr + 0.4f * ta;
        float pb = vb ? (0.6f * dlb + cdr + 0.4f * tb) : -1e30f;

        float pm = fmaxf(pa, pb);
        if (pm > mth) {                   // rare after first pair
            float c = __expf(m - pm);
            ssum *= c; o0 *= c; o1 *= c; o2 *= c; o3 *= c;
            m = pm; mth = pm + 8.0f;
        }
        float wa = __expf(pa - m);
        float wb = __expf(pb - m);        // 0 when masked
        ssum += wa + wb;
        o0 += wa * xa.x + wb * xb.x;
        o1 += wa * xa.y + wb * xb.y;
        o2 += wa * xa.z + wb * xb.z;
        o3 += wa * xa.w + wb * xb.w;

        ia = nia; ib = nib; sva = nsva; svb = nsvb;
        dla = ndla; dlb = ndlb; xa = nxa; xb = nxb;
    }

    float inv = 1.f / (ssum + 1e-16f);
    float4 res;
    res.x = o0 * inv; res.y = o1 * inv; res.z = o2 * inv; res.w = o3 * inv;
    if (AMODE == 1) {
        res.x = (res.x > 0.f) ? res.x : expm1f(res.x);
        res.y = (res.y > 0.f) ? res.y : expm1f(res.y);
        res.z = (res.z > 0.f) ? res.z : expm1f(res.z);
        res.w = (res.w > 0.f) ? res.w : expm1f(res.w);
    } else {
        res.x = (res.x > 0.f) ? res.x : 32.f * expm1f(res.x);
        res.y = (res.y > 0.f) ? res.y : 32.f * expm1f(res.y);
        res.z = (res.z > 0.f) ? res.z : 32.f * expm1f(res.z);
        res.w = (res.w > 0.f) ? res.w : 32.f * expm1f(res.w);
    }
    if (act) *(float4*)&out[((unsigned)node << LSH) + fl * 4] = res;
}

// ================= launcher =================

extern "C" void kernel_launch(void* const* d_in, const int* in_sizes, int n_in,
                              void* d_out, int out_size, void* d_ws, size_t ws_size,
                              hipStream_t stream) {
    const float* x    = (const float*)d_in[0];
    const int*   ei   = (const int*)d_in[1];
    const float* Wl1  = (const float*)d_in[2];
    const float* Wr1  = (const float*)d_in[3];
    const float* att1 = (const float*)d_in[4];
    const float* Wl2  = (const float*)d_in[5];
    const float* Wr2  = (const float*)d_in[6];
    const float* att2 = (const float*)d_in[7];
    const float* Wl3  = (const float*)d_in[8];
    const float* Wr3  = (const float*)d_in[9];
    const float* att3 = (const float*)d_in[10];
    const float* Wl4  = (const float*)d_in[11];
    const float* Wr4  = (const float*)d_in[12];
    const float* att4 = (const float*)d_in[13];

    const int N = in_sizes[0] / 128;
    const int E = in_sizes[1] / 2;
    const int* src = ei;
    const int* dst = ei + E;

    const int nb  = (N + 127) >> BSHIFT;
    const int nbp = (nb + 15) & ~15;

    char* w = (char*)d_ws;
    size_t off = 0;
    auto take = [&](size_t bytes) -> void* {
        void* p = w + off;
        off = (off + bytes + 255) & ~(size_t)255;
        return p;
    };
    int* bcnt8    = (int*)take((size_t)8 * nbp * 4);
    int* bcur8    = (int*)take((size_t)8 * nbp * 4);
    int* bbase    = (int*)take((size_t)(nb + 1) * 4);
    int* rowstart = (int*)take((size_t)(N + 1) * 4);
    int* csr_src  = (int*)take((size_t)E * 4);
    float* dl = (float*)take((size_t)N * 4);
    float* dr = (float*)take((size_t)N * 4);
    float* xl = (float*)take((size_t)N * 64 * 4);
    float* xr = (float*)take((size_t)N * 64 * 4);
    float* hA = (float*)take((size_t)N * 64 * 4);
    float* hB = (float*)take((size_t)N * 64 * 4);
    unsigned short* pWl1 = (unsigned short*)take(2 * 4 * 4 * 512 * 2);
    unsigned short* pWr1 = (unsigned short*)take(2 * 4 * 4 * 512 * 2);
    unsigned short* pWl2 = (unsigned short*)take(2 * 4 * 2 * 512 * 2);
    unsigned short* pWr2 = (unsigned short*)take(2 * 4 * 2 * 512 * 2);
    unsigned short* pWl3 = (unsigned short*)take(2 * 4 * 2 * 512 * 2);
    unsigned short* pWr3 = (unsigned short*)take(2 * 4 * 2 * 512 * 2);
    unsigned short* pWl4 = (unsigned short*)take(2 * 2 * 2 * 512 * 2);
    unsigned short* pWr4 = (unsigned short*)take(2 * 2 * 2 * 512 * 2);
    unsigned* pairs = (unsigned*)hA;   // aliases hA; consumed before layer-1 agg writes hA
    float* outf = (float*)d_out;

    hipMemsetAsync(bcnt8, 0, (size_t)8 * nbp * 4, stream);

    prepack_kernel<<<(2 * 4 * 4 * 512 + 255) / 256, 256, 0, stream>>>(Wl1, Wr1, pWl1, pWr1, 128, 64);
    prepack_kernel<<<(2 * 4 * 2 * 512 + 255) / 256, 256, 0, stream>>>(Wl2, Wr2, pWl2, pWr2, 64, 64);
    prepack_kernel<<<(2 * 4 * 2 * 512 + 255) / 256, 256, 0, stream>>>(Wl3, Wr3, pWl3, pWr3, 64, 64);
    prepack_kernel<<<(2 * 2 * 2 * 512 + 255) / 256, 256, 0, stream>>>(Wl4, Wr4, pWl4, pWr4, 64, 32);

    int kgrid = (E + CH - 1) / CH;
    bucket_hist<<<kgrid, 256, 0, stream>>>(dst, bcnt8, E, nb, nbp);
    bucket_scan<<<1, 1024, 0, stream>>>(bcnt8, bbase, bcur8, rowstart, nb, nbp, E, N);
    bucket_scatter<<<kgrid, 256, 0, stream>>>(src, dst, bcur8, pairs, E, nb, nbp);
    bucket_finalize<<<nb, 256, 0, stream>>>(pairs, bbase, rowstart, csr_src, N);

    int pblk = (N + 63) / 64;
    int agg64 = (N + 15) / 16;    // 4 waves/block, 4 nodes/wave
    int agg32 = (N + 31) / 32;    // 4 waves/block, 8 nodes/wave

    // layer 1: 128 -> 64, ELU
    proj_mfma_kernel<128, 64><<<pblk, 256, 0, stream>>>(x, pWl1, pWr1, att1, xl, xr, dl, dr, N);
    agg_kernel<64, 1><<<agg64, 256, 0, stream>>>(xl, xr, att1, dl, dr, rowstart, csr_src, hA, N, E);

    // layer 2: 64 -> 64, ELU
    proj_mfma_kernel<64, 64><<<pblk, 256, 0, stream>>>(hA, pWl2, pWr2, att2, xl, xr, dl, dr, N);
    agg_kernel<64, 1><<<agg64, 256, 0, stream>>>(xl, xr, att2, dl, dr, rowstart, csr_src, hB, N, E);

    // layer 3: 64 -> 64, ELU
    proj_mfma_kernel<64, 64><<<pblk, 256, 0, stream>>>(hB, pWl3, pWr3, att3, xl, xr, dl, dr, N);
    agg_kernel<64, 1><<<agg64, 256, 0, stream>>>(xl, xr, att3, dl, dr, rowstart, csr_src, hA, N, E);

    // layer 4: 64 -> 32, final ELU (alpha = 32)
    proj_mfma_kernel<64, 32><<<pblk, 256, 0, stream>>>(hA, pWl4, pWr4, att4, xl, xr, dl, dr, N);
    agg_kernel<32, 2><<<agg32, 256, 0, stream>>>(xl, xr, att4, dl, dr, rowstart, csr_src, outf, N, E);
}

// Round 8
// 333.035 us; speedup vs baseline: 1.1997x; 1.1997x over previous
//
#include <hip/hip_runtime.h>
#include <math.h>

typedef __attribute__((ext_vector_type(8))) short bf16x8;
typedef __attribute__((ext_vector_type(4))) float f32x4;
typedef __attribute__((ext_vector_type(4))) _Float16 h4;

#define BSHIFT 7               // 128 nodes per bucket
#define CH 8192                // edges per block in bucket hist/scatter

__device__ inline unsigned short f32_to_bf16_bits(float f) {
    unsigned int u = __float_as_uint(f);
    unsigned int r = (u + 0x7fffu + ((u >> 16) & 1u)) >> 16;   // RNE
    return (unsigned short)r;
}
__device__ inline float bf16_bits_to_f32(unsigned short h) {
    return __uint_as_float(((unsigned int)h) << 16);
}

// single-instruction lane xor-swizzle add (BitMode: (xor<<10)|0x1F)
#define SWZ_ADD(t, imm) \
    t += __int_as_float(__builtin_amdgcn_ds_swizzle(__float_as_int(t), imm))

// ================= 2-level bucket CSR build =================

__global__ __launch_bounds__(256) void bucket_hist(
    const int* __restrict__ dst, int* __restrict__ bcnt8, int E, int nb, int nbp)
{
    __shared__ int h[1024];
    for (int i = threadIdx.x; i < nb; i += 256) h[i] = 0;
    __syncthreads();
    int e0 = blockIdx.x * CH, e1 = min(e0 + CH, E);
    for (int e = e0 + (int)threadIdx.x; e < e1; e += 256)
        atomicAdd(&h[dst[e] >> BSHIFT], 1);
    __syncthreads();
    int* mycnt = bcnt8 + (blockIdx.x & 7) * nbp;
    for (int b = threadIdx.x; b < nb; b += 256) {
        int c = h[b];
        if (c) atomicAdd(&mycnt[b], c);
    }
}

__global__ void bucket_scan(const int* __restrict__ bcnt8, int* __restrict__ bbase,
                            int* __restrict__ bcur8, int* __restrict__ rowstart,
                            int nb, int nbp, int E, int N)
{
    __shared__ int sh[1024];
    int t = threadIdx.x;
    int g8[8];
    int tot = 0;
#pragma unroll
    for (int g = 0; g < 8; ++g) {
        int c = (t < nb) ? bcnt8[g * nbp + t] : 0;
        g8[g] = c; tot += c;
    }
    sh[t] = tot;
    __syncthreads();
    for (int d = 1; d < 1024; d <<= 1) {
        int a = (t >= d) ? sh[t - d] : 0;
        __syncthreads();
        sh[t] += a;
        __syncthreads();
    }
    int base = sh[t] - tot;   // exclusive
    if (t <= nb) bbase[t] = base;
    if (t < nb) {
        int run = base;
#pragma unroll
        for (int g = 0; g < 8; ++g) { bcur8[g * nbp + t] = run; run += g8[g]; }
    }
    if (t == 0) rowstart[N] = E;
}

__global__ __launch_bounds__(256) void bucket_scatter(
    const int* __restrict__ src, const int* __restrict__ dst,
    int* __restrict__ bcur8, unsigned* __restrict__ pairs, int E, int nb, int nbp)
{
    __shared__ int h[1024];
    for (int i = threadIdx.x; i < nb; i += 256) h[i] = 0;
    __syncthreads();
    int e0 = blockIdx.x * CH, e1 = min(e0 + CH, E);
    for (int e = e0 + (int)threadIdx.x; e < e1; e += 256)
        atomicAdd(&h[dst[e] >> BSHIFT], 1);
    __syncthreads();
    int* mycur = bcur8 + (blockIdx.x & 7) * nbp;
    for (int b = threadIdx.x; b < nb; b += 256) {
        int c = h[b];
        if (c) h[b] = atomicAdd(&mycur[b], c);
    }
    __syncthreads();
    for (int e = e0 + (int)threadIdx.x; e < e1; e += 256) {
        int d = dst[e];
        int pos = atomicAdd(&h[d >> BSHIFT], 1);
        pairs[pos] = ((unsigned)src[e] << BSHIFT) | (unsigned)(d & 127);
    }
}

__global__ __launch_bounds__(256) void bucket_finalize(
    const unsigned* __restrict__ pairs, const int* __restrict__ bbase,
    int* __restrict__ rowstart, int* __restrict__ csr_src, int N)
{
    __shared__ int h[128];
    __shared__ int sh[256];
    int b = blockIdx.x;
    int p0 = bbase[b], p1 = bbase[b + 1];
    int t = threadIdx.x;
    if (t < 128) h[t] = 0;
    __syncthreads();
    for (int e = p0 + t; e < p1; e += 256)
        atomicAdd(&h[pairs[e] & 127], 1);
    __syncthreads();
    int v = (t < 128) ? h[t] : 0;
    sh[t] = v;
    __syncthreads();
    for (int d = 1; d < 256; d <<= 1) {
        int a = (t >= d) ? sh[t - d] : 0;
        __syncthreads();
        sh[t] += a;
        __syncthreads();
    }
    if (t < 128) {
        int off = sh[t] - v;
        int node = (b << BSHIFT) + t;
        if (node < N) rowstart[node] = p0 + off;
        h[t] = p0 + off;
    }
    __syncthreads();
    for (int e = p0 + t; e < p1; e += 256) {
        unsigned pr = pairs[e];
        int pos = atomicAdd(&h[pr & 127], 1);
        csr_src[pos] = (int)(pr >> BSHIFT);
    }
}

// ================= weight prepack =================

__global__ void prepack_kernel(const float* __restrict__ Wl, const float* __restrict__ Wr,
                               unsigned short* __restrict__ pWl, unsigned short* __restrict__ pWr,
                               int FIN, int FOUT) {
    int NT = FOUT >> 4, NK = FIN >> 5;
    int part = NT * NK * 512;
    int i = blockIdx.x * blockDim.x + threadIdx.x;
    int m = i / part;
    if (m >= 2) return;
    int ii = i - m * part;
    int j = ii & 7;
    int lane = (ii >> 3) & 63;
    int rest = ii >> 9;
    int ks = rest % NK;
    int t = rest / NK;
    int k = ks * 32 + (lane >> 4) * 8 + j;
    int c = t * 16 + (lane & 15);
    const float* W = m ? Wr : Wl;
    unsigned short* P = m ? pWr : pWl;
    float w = W[(size_t)k * FOUT + c];
    unsigned short hi = f32_to_bf16_bits(w);
    unsigned short lo = f32_to_bf16_bits(w - bf16_bits_to_f32(hi));
    P[ii] = hi;
    P[part + ii] = lo;
}

// ================= MFMA projection + att-dot epilogue =================
// xl written as fp16 (agg gather table); xr/dl/dr stay f32.

template<int FIN, int FOUT>
__global__ __launch_bounds__(256) void proj_mfma_kernel(
    const float* __restrict__ x,
    const unsigned short* __restrict__ pWl, const unsigned short* __restrict__ pWr,
    const float* __restrict__ att,
    _Float16* __restrict__ xlh, float* __restrict__ xr,
    float* __restrict__ dl, float* __restrict__ dr, int n)
{
    constexpr int NT = FOUT >> 4;
    constexpr int NK = FIN >> 5;
    constexpr int PART = NT * NK * 512;
    const int wave = threadIdx.x >> 6;
    const int lane = threadIdx.x & 63;
    const int row0 = blockIdx.x * 64 + wave * 16;
    int arow = row0 + (lane & 15);
    if (arow >= n) arow = n - 1;
    const int khalf = lane >> 4;

    f32x4 accl[NT], accr[NT];
#pragma unroll
    for (int t = 0; t < NT; ++t) {
        accl[t] = (f32x4){0.f, 0.f, 0.f, 0.f};
        accr[t] = (f32x4){0.f, 0.f, 0.f, 0.f};
    }

    const float* xrow = x + (size_t)arow * FIN + khalf * 8;
#pragma unroll
    for (int ks = 0; ks < NK; ++ks) {
        float4 a0 = *(const float4*)(xrow + ks * 32);
        float4 a1 = *(const float4*)(xrow + ks * 32 + 4);
        float av[8] = {a0.x, a0.y, a0.z, a0.w, a1.x, a1.y, a1.z, a1.w};
        bf16x8 ah, al;
#pragma unroll
        for (int j = 0; j < 8; ++j) {
            unsigned short h = f32_to_bf16_bits(av[j]);
            ah[j] = (short)h;
            al[j] = (short)f32_to_bf16_bits(av[j] - bf16_bits_to_f32(h));
        }
#pragma unroll
        for (int t = 0; t < NT; ++t) {
            const unsigned short* bpl = pWl + ((size_t)(t * NK + ks) * 64 + lane) * 8;
            bf16x8 bh  = *(const bf16x8*)bpl;
            bf16x8 blo = *(const bf16x8*)(bpl + PART);
            accl[t] = __builtin_amdgcn_mfma_f32_16x16x32_bf16(ah, bh,  accl[t], 0, 0, 0);
            accl[t] = __builtin_amdgcn_mfma_f32_16x16x32_bf16(ah, blo, accl[t], 0, 0, 0);
            accl[t] = __builtin_amdgcn_mfma_f32_16x16x32_bf16(al, bh,  accl[t], 0, 0, 0);
            const unsigned short* bpr = pWr + ((size_t)(t * NK + ks) * 64 + lane) * 8;
            bh  = *(const bf16x8*)bpr;
            blo = *(const bf16x8*)(bpr + PART);
            accr[t] = __builtin_amdgcn_mfma_f32_16x16x32_bf16(ah, bh,  accr[t], 0, 0, 0);
            accr[t] = __builtin_amdgcn_mfma_f32_16x16x32_bf16(ah, blo, accr[t], 0, 0, 0);
            accr[t] = __builtin_amdgcn_mfma_f32_16x16x32_bf16(al, bh,  accr[t], 0, 0, 0);
        }
    }

    const int orow0 = row0 + khalf * 4;
    const int colb = lane & 15;
    float attc[NT];
#pragma unroll
    for (int t = 0; t < NT; ++t) attc[t] = att[t * 16 + colb];

#pragma unroll
    for (int t = 0; t < NT; ++t) {
        int col = t * 16 + colb;
#pragma unroll
        for (int r = 0; r < 4; ++r) {
            int rr = orow0 + r;
            if (rr < n) {
                xlh[(size_t)rr * FOUT + col] = (_Float16)accl[t][r];
                xr[(size_t)rr * FOUT + col] = accr[t][r];
            }
        }
    }
#pragma unroll
    for (int r = 0; r < 4; ++r) {
        float pl = 0.f, pr = 0.f;
#pragma unroll
        for (int t = 0; t < NT; ++t) { pl += accl[t][r] * attc[t]; pr += accr[t][r] * attc[t]; }
#pragma unroll
        for (int off = 1; off < 16; off <<= 1) {
            pl += __shfl_xor(pl, off);
            pr += __shfl_xor(pr, off);
        }
        int rr = orow0 + r;
        if (colb == 0 && rr < n) { dl[rr] = pl; dr[rr] = pr; }
    }
}

// ================= per-dst online-softmax aggregation =================
// Group-per-node, fp16 gather table (8B/lane), 2-edge pipeline with
// segment-clamped prefetch. score = 0.6*(dl+dr) + 0.4*sum(att*|s|);
// pair-merged defer-max (thr 8). f32 accumulation.

template<int F, int AMODE>
__global__ __launch_bounds__(256) void agg_kernel(
    const _Float16* __restrict__ xlh, const float* __restrict__ xr, const float* __restrict__ att,
    const float* __restrict__ dl, const float* __restrict__ dr,
    const int* __restrict__ rowstart, const int* __restrict__ csr_src,
    float* __restrict__ out, int n, int E)
{
    constexpr int LPE = F / 4;            // lanes per node
    constexpr int LSH = (F == 64) ? 6 : 5;
    constexpr int NPG = 64 / LPE;         // nodes per wave

    int wv  = (blockIdx.x * blockDim.x + threadIdx.x) >> 6;
    int lane = threadIdx.x & 63;
    int grp = lane / LPE;
    int fl  = lane % LPE;
    int node = wv * NPG + grp;
    bool act = node < n;
    int nc = act ? node : 0;

    float4 xrv  = *(const float4*)&xr[((unsigned)nc << LSH) + fl * 4];
    float4 attv = *(const float4*)&att[fl * 4];
    float cdr = 0.6f * dr[nc];

    int s0 = rowstart[nc];
    int s1 = act ? rowstart[nc + 1] : s0;
    int s1c = min(max(s1 - 1, s0), E - 1);   // clamp inside own segment

    float m = -1e30f, mth = -1e30f, ssum = 0.f;
    float o0 = 0.f, o1 = 0.f, o2 = 0.f, o3 = 0.f;

    // pipeline preload for edge pair (ia, ib)
    int ia = s0, ib = s0 + 1;
    int sva = csr_src[min(ia, s1c)];
    int svb = csr_src[min(ib, s1c)];
    float dla = dl[sva], dlb = dl[svb];
    h4 xa = *(const h4*)(xlh + (((unsigned)sva << LSH) + fl * 4));
    h4 xb = *(const h4*)(xlh + (((unsigned)svb << LSH) + fl * 4));

    while (ia < s1) {
        // prefetch next pair (segment-clamped: re-reads hot last row at tail)
        int nia = ia + 2, nib = ib + 2;
        int nsva = csr_src[min(nia, s1c)];
        int nsvb = csr_src[min(nib, s1c)];
        float ndla = dl[nsva], ndlb = dl[nsvb];
        h4 nxa = *(const h4*)(xlh + (((unsigned)nsva << LSH) + fl * 4));
        h4 nxb = *(const h4*)(xlh + (((unsigned)nsvb << LSH) + fl * 4));

        float xa0 = (float)xa[0], xa1 = (float)xa[1], xa2 = (float)xa[2], xa3 = (float)xa[3];
        float xb0 = (float)xb[0], xb1 = (float)xb[1], xb2 = (float)xb[2], xb3 = (float)xb[3];

        bool vb = ib < s1;
        float ta = attv.x * fabsf(xa0 + xrv.x)
                 + attv.y * fabsf(xa1 + xrv.y)
                 + attv.z * fabsf(xa2 + xrv.z)
                 + attv.w * fabsf(xa3 + xrv.w);
        float tb = attv.x * fabsf(xb0 + xrv.x)
                 + attv.y * fabsf(xb1 + xrv.y)
                 + attv.z * fabsf(xb2 + xrv.z)
                 + attv.w * fabsf(xb3 + xrv.w);
        SWZ_ADD(ta, 0x041F); SWZ_ADD(tb, 0x041F);   // xor 1
        SWZ_ADD(ta, 0x081F); SWZ_ADD(tb, 0x081F);   // xor 2
        SWZ_ADD(ta, 0x101F); SWZ_ADD(tb, 0x101F);   // xor 4
        if (LPE == 16) { SWZ_ADD(ta, 0x201F); SWZ_ADD(tb, 0x201F); }  // xor 8

        float pa = 0.6f * dla + cdr + 0.4f * ta;
        float pb = vb ? (0.6f * dlb + cdr + 0.4f * tb) : -1e30f;

        float pm = fmaxf(pa, pb);
        if (pm > mth) {                   // rare after first pair
            float c = __expf(m - pm);
            ssum *= c; o0 *= c; o1 *= c; o2 *= c; o3 *= c;
            m = pm; mth = pm + 8.0f;
        }
        float wa = __expf(pa - m);
        float wb = __expf(pb - m);        // 0 when masked
        ssum += wa + wb;
        o0 += wa * xa0 + wb * xb0;
        o1 += wa * xa1 + wb * xb1;
        o2 += wa * xa2 + wb * xb2;
        o3 += wa * xa3 + wb * xb3;

        ia = nia; ib = nib;
        dla = ndla; dlb = ndlb; xa = nxa; xb = nxb;
    }

    float inv = 1.f / (ssum + 1e-16f);
    float4 res;
    res.x = o0 * inv; res.y = o1 * inv; res.z = o2 * inv; res.w = o3 * inv;
    if (AMODE == 1) {
        res.x = (res.x > 0.f) ? res.x : expm1f(res.x);
        res.y = (res.y > 0.f) ? res.y : expm1f(res.y);
        res.z = (res.z > 0.f) ? res.z : expm1f(res.z);
        res.w = (res.w > 0.f) ? res.w : expm1f(res.w);
    } else {
        res.x = (res.x > 0.f) ? res.x : 32.f * expm1f(res.x);
        res.y = (res.y > 0.f) ? res.y : 32.f * expm1f(res.y);
        res.z = (res.z > 0.f) ? res.z : 32.f * expm1f(res.z);
        res.w = (res.w > 0.f) ? res.w : 32.f * expm1f(res.w);
    }
    if (act) *(float4*)&out[((unsigned)node << LSH) + fl * 4] = res;
}

// ================= launcher =================

extern "C" void kernel_launch(void* const* d_in, const int* in_sizes, int n_in,
                              void* d_out, int out_size, void* d_ws, size_t ws_size,
                              hipStream_t stream) {
    const float* x    = (const float*)d_in[0];
    const int*   ei   = (const int*)d_in[1];
    const float* Wl1  = (const float*)d_in[2];
    const float* Wr1  = (const float*)d_in[3];
    const float* att1 = (const float*)d_in[4];
    const float* Wl2  = (const float*)d_in[5];
    const float* Wr2  = (const float*)d_in[6];
    const float* att2 = (const float*)d_in[7];
    const float* Wl3  = (const float*)d_in[8];
    const float* Wr3  = (const float*)d_in[9];
    const float* att3 = (const float*)d_in[10];
    const float* Wl4  = (const float*)d_in[11];
    const float* Wr4  = (const float*)d_in[12];
    const float* att4 = (const float*)d_in[13];

    const int N = in_sizes[0] / 128;
    const int E = in_sizes[1] / 2;
    const int* src = ei;
    const int* dst = ei + E;

    const int nb  = (N + 127) >> BSHIFT;
    const int nbp = (nb + 15) & ~15;

    char* w = (char*)d_ws;
    size_t off = 0;
    auto take = [&](size_t bytes) -> void* {
        void* p = w + off;
        off = (off + bytes + 255) & ~(size_t)255;
        return p;
    };
    int* bcnt8    = (int*)take((size_t)8 * nbp * 4);
    int* bcur8    = (int*)take((size_t)8 * nbp * 4);
    int* bbase    = (int*)take((size_t)(nb + 1) * 4);
    int* rowstart = (int*)take((size_t)(N + 1) * 4);
    int* csr_src  = (int*)take((size_t)E * 4);
    float* dl = (float*)take((size_t)N * 4);
    float* dr = (float*)take((size_t)N * 4);
    _Float16* xlh = (_Float16*)take((size_t)N * 64 * 2);
    float* xr = (float*)take((size_t)N * 64 * 4);
    float* hA = (float*)take((size_t)N * 64 * 4);
    float* hB = (float*)take((size_t)N * 64 * 4);
    unsigned short* pWl1 = (unsigned short*)take(2 * 4 * 4 * 512 * 2);
    unsigned short* pWr1 = (unsigned short*)take(2 * 4 * 4 * 512 * 2);
    unsigned short* pWl2 = (unsigned short*)take(2 * 4 * 2 * 512 * 2);
    unsigned short* pWr2 = (unsigned short*)take(2 * 4 * 2 * 512 * 2);
    unsigned short* pWl3 = (unsigned short*)take(2 * 4 * 2 * 512 * 2);
    unsigned short* pWr3 = (unsigned short*)take(2 * 4 * 2 * 512 * 2);
    unsigned short* pWl4 = (unsigned short*)take(2 * 2 * 2 * 512 * 2);
    unsigned short* pWr4 = (unsigned short*)take(2 * 2 * 2 * 512 * 2);
    unsigned* pairs = (unsigned*)hA;   // aliases hA; consumed before layer-1 agg writes hA
    float* outf = (float*)d_out;

    hipMemsetAsync(bcnt8, 0, (size_t)8 * nbp * 4, stream);

    prepack_kernel<<<(2 * 4 * 4 * 512 + 255) / 256, 256, 0, stream>>>(Wl1, Wr1, pWl1, pWr1, 128, 64);
    prepack_kernel<<<(2 * 4 * 2 * 512 + 255) / 256, 256, 0, stream>>>(Wl2, Wr2, pWl2, pWr2, 64, 64);
    prepack_kernel<<<(2 * 4 * 2 * 512 + 255) / 256, 256, 0, stream>>>(Wl3, Wr3, pWl3, pWr3, 64, 64);
    prepack_kernel<<<(2 * 2 * 2 * 512 + 255) / 256, 256, 0, stream>>>(Wl4, Wr4, pWl4, pWr4, 64, 32);

    int kgrid = (E + CH - 1) / CH;
    bucket_hist<<<kgrid, 256, 0, stream>>>(dst, bcnt8, E, nb, nbp);
    bucket_scan<<<1, 1024, 0, stream>>>(bcnt8, bbase, bcur8, rowstart, nb, nbp, E, N);
    bucket_scatter<<<kgrid, 256, 0, stream>>>(src, dst, bcur8, pairs, E, nb, nbp);
    bucket_finalize<<<nb, 256, 0, stream>>>(pairs, bbase, rowstart, csr_src, N);

    int pblk = (N + 63) / 64;
    int agg64 = (N + 15) / 16;    // 4 waves/block, 4 nodes/wave
    int agg32 = (N + 31) / 32;    // 4 waves/block, 8 nodes/wave

    // layer 1: 128 -> 64, ELU
    proj_mfma_kernel<128, 64><<<pblk, 256, 0, stream>>>(x, pWl1, pWr1, att1, xlh, xr, dl, dr, N);
    agg_kernel<64, 1><<<agg64, 256, 0, stream>>>(xlh, xr, att1, dl, dr, rowstart, csr_src, hA, N, E);

    // layer 2: 64 -> 64, ELU
    proj_mfma_kernel<64, 64><<<pblk, 256, 0, stream>>>(hA, pWl2, pWr2, att2, xlh, xr, dl, dr, N);
    agg_kernel<64, 1><<<agg64, 256, 0, stream>>>(xlh, xr, att2, dl, dr, rowstart, csr_src, hB, N, E);

    // layer 3: 64 -> 64, ELU
    proj_mfma_kernel<64, 64><<<pblk, 256, 0, stream>>>(hB, pWl3, pWr3, att3, xlh, xr, dl, dr, N);
    agg_kernel<64, 1><<<agg64, 256, 0, stream>>>(xlh, xr, att3, dl, dr, rowstart, csr_src, hA, N, E);

    // layer 4: 64 -> 32, final ELU (alpha = 32)
    proj_mfma_kernel<64, 32><<<pblk, 256, 0, stream>>>(hA, pWl4, pWr4, att4, xlh, xr, dl, dr, N);
    agg_kernel<32, 2><<<agg32, 256, 0, stream>>>(xlh, xr, att4, dl, dr, rowstart, csr_src, outf, N, E);
}

// Round 9
// 304.557 us; speedup vs baseline: 1.3119x; 1.0935x over previous
//
#include <hip/hip_runtime.h>
#include <math.h>

typedef __attribute__((ext_vector_type(8))) short bf16x8;
typedef __attribute__((ext_vector_type(4))) float f32x4;
typedef __attribute__((ext_vector_type(2))) _Float16 h2;

#define BSHIFT 7               // 128 nodes per bucket
#define CH 8192                // edges per block in bucket hist/scatter

__device__ inline unsigned short f32_to_bf16_bits(float f) {
    unsigned int u = __float_as_uint(f);
    unsigned int r = (u + 0x7fffu + ((u >> 16) & 1u)) >> 16;   // RNE
    return (unsigned short)r;
}
__device__ inline float bf16_bits_to_f32(unsigned short h) {
    return __uint_as_float(((unsigned int)h) << 16);
}
__device__ inline h2 u2h(unsigned u) { return __builtin_bit_cast(h2, u); }
__device__ inline unsigned h2u(h2 h) { return __builtin_bit_cast(unsigned, h); }

// single-instruction lane xor-swizzle add (BitMode: (xor<<10)|0x1F)
#define SWZ_ADD(t, imm) \
    t += __int_as_float(__builtin_amdgcn_ds_swizzle(__float_as_int(t), imm))

// fp16 pair dot with f32 accumulate (v_dot2_f32_f16)
__device__ inline float dot2acc(h2 a, h2 b, float c) {
#if defined(__has_builtin)
#if __has_builtin(__builtin_amdgcn_fdot2)
    return __builtin_amdgcn_fdot2(a, b, c, false);
#else
    return c + (float)a[0] * (float)b[0] + (float)a[1] * (float)b[1];
#endif
#else
    return c + (float)a[0] * (float)b[0] + (float)a[1] * (float)b[1];
#endif
}

// ================= 2-level bucket CSR build =================

__global__ __launch_bounds__(256) void bucket_hist(
    const int* __restrict__ dst, int* __restrict__ bcnt8, int E, int nb, int nbp)
{
    __shared__ int h[1024];
    for (int i = threadIdx.x; i < nb; i += 256) h[i] = 0;
    __syncthreads();
    int e0 = blockIdx.x * CH, e1 = min(e0 + CH, E);
    for (int e = e0 + (int)threadIdx.x; e < e1; e += 256)
        atomicAdd(&h[dst[e] >> BSHIFT], 1);
    __syncthreads();
    int* mycnt = bcnt8 + (blockIdx.x & 7) * nbp;
    for (int b = threadIdx.x; b < nb; b += 256) {
        int c = h[b];
        if (c) atomicAdd(&mycnt[b], c);
    }
}

__global__ void bucket_scan(const int* __restrict__ bcnt8, int* __restrict__ bbase,
                            int* __restrict__ bcur8, int* __restrict__ rowstart,
                            int nb, int nbp, int E, int N)
{
    __shared__ int sh[1024];
    int t = threadIdx.x;
    int g8[8];
    int tot = 0;
#pragma unroll
    for (int g = 0; g < 8; ++g) {
        int c = (t < nb) ? bcnt8[g * nbp + t] : 0;
        g8[g] = c; tot += c;
    }
    sh[t] = tot;
    __syncthreads();
    for (int d = 1; d < 1024; d <<= 1) {
        int a = (t >= d) ? sh[t - d] : 0;
        __syncthreads();
        sh[t] += a;
        __syncthreads();
    }
    int base = sh[t] - tot;   // exclusive
    if (t <= nb) bbase[t] = base;
    if (t < nb) {
        int run = base;
#pragma unroll
        for (int g = 0; g < 8; ++g) { bcur8[g * nbp + t] = run; run += g8[g]; }
    }
    if (t == 0) rowstart[N] = E;
}

__global__ __launch_bounds__(256) void bucket_scatter(
    const int* __restrict__ src, const int* __restrict__ dst,
    int* __restrict__ bcur8, unsigned* __restrict__ pairs, int E, int nb, int nbp)
{
    __shared__ int h[1024];
    for (int i = threadIdx.x; i < nb; i += 256) h[i] = 0;
    __syncthreads();
    int e0 = blockIdx.x * CH, e1 = min(e0 + CH, E);
    for (int e = e0 + (int)threadIdx.x; e < e1; e += 256)
        atomicAdd(&h[dst[e] >> BSHIFT], 1);
    __syncthreads();
    int* mycur = bcur8 + (blockIdx.x & 7) * nbp;
    for (int b = threadIdx.x; b < nb; b += 256) {
        int c = h[b];
        if (c) h[b] = atomicAdd(&mycur[b], c);
    }
    __syncthreads();
    for (int e = e0 + (int)threadIdx.x; e < e1; e += 256) {
        int d = dst[e];
        int pos = atomicAdd(&h[d >> BSHIFT], 1);
        pairs[pos] = ((unsigned)src[e] << BSHIFT) | (unsigned)(d & 127);
    }
}

__global__ __launch_bounds__(256) void bucket_finalize(
    const unsigned* __restrict__ pairs, const int* __restrict__ bbase,
    int* __restrict__ rowstart, int* __restrict__ csr_src, int N)
{
    __shared__ int h[128];
    __shared__ int sh[256];
    int b = blockIdx.x;
    int p0 = bbase[b], p1 = bbase[b + 1];
    int t = threadIdx.x;
    if (t < 128) h[t] = 0;
    __syncthreads();
    for (int e = p0 + t; e < p1; e += 256)
        atomicAdd(&h[pairs[e] & 127], 1);
    __syncthreads();
    int v = (t < 128) ? h[t] : 0;
    sh[t] = v;
    __syncthreads();
    for (int d = 1; d < 256; d <<= 1) {
        int a = (t >= d) ? sh[t - d] : 0;
        __syncthreads();
        sh[t] += a;
        __syncthreads();
    }
    if (t < 128) {
        int off = sh[t] - v;
        int node = (b << BSHIFT) + t;
        if (node < N) rowstart[node] = p0 + off;
        h[t] = p0 + off;
    }
    __syncthreads();
    for (int e = p0 + t; e < p1; e += 256) {
        unsigned pr = pairs[e];
        int pos = atomicAdd(&h[pr & 127], 1);
        csr_src[pos] = (int)(pr >> BSHIFT);
    }
}

// ================= weight prepack =================

__global__ void prepack_kernel(const float* __restrict__ Wl, const float* __restrict__ Wr,
                               unsigned short* __restrict__ pWl, unsigned short* __restrict__ pWr,
                               int FIN, int FOUT) {
    int NT = FOUT >> 4, NK = FIN >> 5;
    int part = NT * NK * 512;
    int i = blockIdx.x * blockDim.x + threadIdx.x;
    int m = i / part;
    if (m >= 2) return;
    int ii = i - m * part;
    int j = ii & 7;
    int lane = (ii >> 3) & 63;
    int rest = ii >> 9;
    int ks = rest % NK;
    int t = rest / NK;
    int k = ks * 32 + (lane >> 4) * 8 + j;
    int c = t * 16 + (lane & 15);
    const float* W = m ? Wr : Wl;
    unsigned short* P = m ? pWr : pWl;
    float w = W[(size_t)k * FOUT + c];
    unsigned short hi = f32_to_bf16_bits(w);
    unsigned short lo = f32_to_bf16_bits(w - bf16_bits_to_f32(hi));
    P[ii] = hi;
    P[part + ii] = lo;
}

// ================= MFMA projection + att-dot epilogue =================
// xl AND xr written as fp16 (agg tables); dl/dr stay f32.

template<int FIN, int FOUT>
__global__ __launch_bounds__(256) void proj_mfma_kernel(
    const float* __restrict__ x,
    const unsigned short* __restrict__ pWl, const unsigned short* __restrict__ pWr,
    const float* __restrict__ att,
    _Float16* __restrict__ xlh, _Float16* __restrict__ xrh,
    float* __restrict__ dl, float* __restrict__ dr, int n)
{
    constexpr int NT = FOUT >> 4;
    constexpr int NK = FIN >> 5;
    constexpr int PART = NT * NK * 512;
    const int wave = threadIdx.x >> 6;
    const int lane = threadIdx.x & 63;
    const int row0 = blockIdx.x * 64 + wave * 16;
    int arow = row0 + (lane & 15);
    if (arow >= n) arow = n - 1;
    const int khalf = lane >> 4;

    f32x4 accl[NT], accr[NT];
#pragma unroll
    for (int t = 0; t < NT; ++t) {
        accl[t] = (f32x4){0.f, 0.f, 0.f, 0.f};
        accr[t] = (f32x4){0.f, 0.f, 0.f, 0.f};
    }

    const float* xrow = x + (size_t)arow * FIN + khalf * 8;
#pragma unroll
    for (int ks = 0; ks < NK; ++ks) {
        float4 a0 = *(const float4*)(xrow + ks * 32);
        float4 a1 = *(const float4*)(xrow + ks * 32 + 4);
        float av[8] = {a0.x, a0.y, a0.z, a0.w, a1.x, a1.y, a1.z, a1.w};
        bf16x8 ah, al;
#pragma unroll
        for (int j = 0; j < 8; ++j) {
            unsigned short h = f32_to_bf16_bits(av[j]);
            ah[j] = (short)h;
            al[j] = (short)f32_to_bf16_bits(av[j] - bf16_bits_to_f32(h));
        }
#pragma unroll
        for (int t = 0; t < NT; ++t) {
            const unsigned short* bpl = pWl + ((size_t)(t * NK + ks) * 64 + lane) * 8;
            bf16x8 bh  = *(const bf16x8*)bpl;
            bf16x8 blo = *(const bf16x8*)(bpl + PART);
            accl[t] = __builtin_amdgcn_mfma_f32_16x16x32_bf16(ah, bh,  accl[t], 0, 0, 0);
            accl[t] = __builtin_amdgcn_mfma_f32_16x16x32_bf16(ah, blo, accl[t], 0, 0, 0);
            accl[t] = __builtin_amdgcn_mfma_f32_16x16x32_bf16(al, bh,  accl[t], 0, 0, 0);
            const unsigned short* bpr = pWr + ((size_t)(t * NK + ks) * 64 + lane) * 8;
            bh  = *(const bf16x8*)bpr;
            blo = *(const bf16x8*)(bpr + PART);
            accr[t] = __builtin_amdgcn_mfma_f32_16x16x32_bf16(ah, bh,  accr[t], 0, 0, 0);
            accr[t] = __builtin_amdgcn_mfma_f32_16x16x32_bf16(ah, blo, accr[t], 0, 0, 0);
            accr[t] = __builtin_amdgcn_mfma_f32_16x16x32_bf16(al, bh,  accr[t], 0, 0, 0);
        }
    }

    const int orow0 = row0 + khalf * 4;
    const int colb = lane & 15;
    float attc[NT];
#pragma unroll
    for (int t = 0; t < NT; ++t) attc[t] = att[t * 16 + colb];

#pragma unroll
    for (int t = 0; t < NT; ++t) {
        int col = t * 16 + colb;
#pragma unroll
        for (int r = 0; r < 4; ++r) {
            int rr = orow0 + r;
            if (rr < n) {
                xlh[(size_t)rr * FOUT + col] = (_Float16)accl[t][r];
                xrh[(size_t)rr * FOUT + col] = (_Float16)accr[t][r];
            }
        }
    }
#pragma unroll
    for (int r = 0; r < 4; ++r) {
        float pl = 0.f, pr = 0.f;
#pragma unroll
        for (int t = 0; t < NT; ++t) { pl += accl[t][r] * attc[t]; pr += accr[t][r] * attc[t]; }
#pragma unroll
        for (int off = 1; off < 16; off <<= 1) {
            pl += __shfl_xor(pl, off);
            pr += __shfl_xor(pr, off);
        }
        int rr = orow0 + r;
        if (colb == 0 && rr < n) { dl[rr] = pl; dr[rr] = pr; }
    }
}

// ================= per-dst online-softmax aggregation =================
// Group-per-node, 8 features/lane (LPE = F/8), packed fp16 math:
// e = v_pk_add_f16, |e| = packed AND, att.|e| = v_dot2_f32_f16.
// 2-edge pipeline, segment-clamped prefetch, pair-merged defer-max.
// score = 0.6*(dl[src]+dr[dst]) + 0.4*sum(att*|s|); f32 accumulation.

template<int F, int AMODE>
__global__ __launch_bounds__(256) void agg_kernel(
    const _Float16* __restrict__ xlh, const _Float16* __restrict__ xrh,
    const float* __restrict__ att,
    const float* __restrict__ dl, const float* __restrict__ dr,
    const int* __restrict__ rowstart, const int* __restrict__ csr_src,
    float* __restrict__ out, int n, int E)
{
    constexpr int LPE = F / 8;            // lanes per node (8 feats/lane)
    constexpr int LSH = (F == 64) ? 6 : 5;
    constexpr int NPG = 64 / LPE;         // nodes per wave

    int wv  = (blockIdx.x * blockDim.x + threadIdx.x) >> 6;
    int lane = threadIdx.x & 63;
    int grp = lane / LPE;
    int fl  = lane % LPE;
    int node = wv * NPG + grp;
    bool act = node < n;
    int nc = act ? node : 0;

    // xr row (fp16, 16B) and att (converted to h2) for this lane's 8 features
    float4 xrraw = *(const float4*)(xrh + (((unsigned)nc << LSH) + fl * 8));
    h2 xrv[4];
#pragma unroll
    for (int j = 0; j < 4; ++j) xrv[j] = u2h(((const unsigned*)&xrraw)[j]);
    h2 atth[4];
#pragma unroll
    for (int j = 0; j < 4; ++j) {
        atth[j][0] = (_Float16)att[fl * 8 + 2 * j];
        atth[j][1] = (_Float16)att[fl * 8 + 2 * j + 1];
    }
    float cdr = 0.6f * dr[nc];

    int s0 = rowstart[nc];
    int s1 = act ? rowstart[nc + 1] : s0;
    int s1c = min(max(s1 - 1, s0), E - 1);   // clamp inside own segment

    float m = -1e30f, mth = -1e30f, ssum = 0.f;
    float o[8];
#pragma unroll
    for (int j = 0; j < 8; ++j) o[j] = 0.f;

    // pipeline preload for edge pair (ia, ib)
    int ia = s0, ib = s0 + 1;
    int sva = csr_src[min(ia, s1c)];
    int svb = csr_src[min(ib, s1c)];
    float dla = dl[sva], dlb = dl[svb];
    float4 rawa = *(const float4*)(xlh + (((unsigned)sva << LSH) + fl * 8));
    float4 rawb = *(const float4*)(xlh + (((unsigned)svb << LSH) + fl * 8));

    while (ia < s1) {
        // prefetch next pair (segment-clamped)
        int nia = ia + 2, nib = ib + 2;
        int nsva = csr_src[min(nia, s1c)];
        int nsvb = csr_src[min(nib, s1c)];
        float ndla = dl[nsva], ndlb = dl[nsvb];
        float4 nrawa = *(const float4*)(xlh + (((unsigned)nsva << LSH) + fl * 8));
        float4 nrawb = *(const float4*)(xlh + (((unsigned)nsvb << LSH) + fl * 8));

        h2 a[4], b[4];
#pragma unroll
        for (int j = 0; j < 4; ++j) {
            a[j] = u2h(((const unsigned*)&rawa)[j]);
            b[j] = u2h(((const unsigned*)&rawb)[j]);
        }

        bool vb = ib < s1;
        float ta = 0.f, tb = 0.f;
#pragma unroll
        for (int j = 0; j < 4; ++j) {
            h2 ea = a[j] + xrv[j];                       // v_pk_add_f16
            h2 eb = b[j] + xrv[j];
            ea = u2h(h2u(ea) & 0x7FFF7FFFu);             // packed |.|
            eb = u2h(h2u(eb) & 0x7FFF7FFFu);
            ta = dot2acc(atth[j], ea, ta);               // v_dot2_f32_f16
            tb = dot2acc(atth[j], eb, tb);
        }
        SWZ_ADD(ta, 0x041F); SWZ_ADD(tb, 0x041F);        // xor 1
        SWZ_ADD(ta, 0x081F); SWZ_ADD(tb, 0x081F);        // xor 2
        if (LPE == 8) { SWZ_ADD(ta, 0x101F); SWZ_ADD(tb, 0x101F); }  // xor 4

        float pa = 0.6f * dla + cdr + 0.4f * ta;
        float pb = vb ? (0.6f * dlb + cdr + 0.4f * tb) : -1e30f;

        float pm = fmaxf(pa, pb);
        if (pm > mth) {                   // rare after first pair
            float c = __expf(m - pm);
            ssum *= c;
#pragma unroll
            for (int j = 0; j < 8; ++j) o[j] *= c;
            m = pm; mth = pm + 8.0f;
        }
        float wa = __expf(pa - m);
        float wb = __expf(pb - m);        // 0 when masked
        ssum += wa + wb;
#pragma unroll
        for (int j = 0; j < 4; ++j) {
            o[2 * j]     += wa * (float)a[j][0] + wb * (float)b[j][0];
            o[2 * j + 1] += wa * (float)a[j][1] + wb * (float)b[j][1];
        }

        ia = nia; ib = nib;
        dla = ndla; dlb = ndlb; rawa = nrawa; rawb = nrawb;
    }

    float inv = 1.f / (ssum + 1e-16f);
    float res[8];
#pragma unroll
    for (int j = 0; j < 8; ++j) {
        float r = o[j] * inv;
        if (AMODE == 1) r = (r > 0.f) ? r : expm1f(r);
        else            r = (r > 0.f) ? r : 32.f * expm1f(r);
        res[j] = r;
    }
    if (act) {
        float* op = out + (((unsigned)node << LSH) + fl * 8);
        *(float4*)op       = (float4){res[0], res[1], res[2], res[3]};
        *(float4*)(op + 4) = (float4){res[4], res[5], res[6], res[7]};
    }
}

// ================= launcher =================

extern "C" void kernel_launch(void* const* d_in, const int* in_sizes, int n_in,
                              void* d_out, int out_size, void* d_ws, size_t ws_size,
                              hipStream_t stream) {
    const float* x    = (const float*)d_in[0];
    const int*   ei   = (const int*)d_in[1];
    const float* Wl1  = (const float*)d_in[2];
    const float* Wr1  = (const float*)d_in[3];
    const float* att1 = (const float*)d_in[4];
    const float* Wl2  = (const float*)d_in[5];
    const float* Wr2  = (const float*)d_in[6];
    const float* att2 = (const float*)d_in[7];
    const float* Wl3  = (const float*)d_in[8];
    const float* Wr3  = (const float*)d_in[9];
    const float* att3 = (const float*)d_in[10];
    const float* Wl4  = (const float*)d_in[11];
    const float* Wr4  = (const float*)d_in[12];
    const float* att4 = (const float*)d_in[13];

    const int N = in_sizes[0] / 128;
    const int E = in_sizes[1] / 2;
    const int* src = ei;
    const int* dst = ei + E;

    const int nb  = (N + 127) >> BSHIFT;
    const int nbp = (nb + 15) & ~15;

    char* w = (char*)d_ws;
    size_t off = 0;
    auto take = [&](size_t bytes) -> void* {
        void* p = w + off;
        off = (off + bytes + 255) & ~(size_t)255;
        return p;
    };
    int* bcnt8    = (int*)take((size_t)8 * nbp * 4);
    int* bcur8    = (int*)take((size_t)8 * nbp * 4);
    int* bbase    = (int*)take((size_t)(nb + 1) * 4);
    int* rowstart = (int*)take((size_t)(N + 1) * 4);
    int* csr_src  = (int*)take((size_t)E * 4);
    float* dl = (float*)take((size_t)N * 4);
    float* dr = (float*)take((size_t)N * 4);
    _Float16* xlh = (_Float16*)take((size_t)N * 64 * 2);
    _Float16* xrh = (_Float16*)take((size_t)N * 64 * 2);
    float* hA = (float*)take((size_t)N * 64 * 4);
    float* hB = (float*)take((size_t)N * 64 * 4);
    unsigned short* pWl1 = (unsigned short*)take(2 * 4 * 4 * 512 * 2);
    unsigned short* pWr1 = (unsigned short*)take(2 * 4 * 4 * 512 * 2);
    unsigned short* pWl2 = (unsigned short*)take(2 * 4 * 2 * 512 * 2);
    unsigned short* pWr2 = (unsigned short*)take(2 * 4 * 2 * 512 * 2);
    unsigned short* pWl3 = (unsigned short*)take(2 * 4 * 2 * 512 * 2);
    unsigned short* pWr3 = (unsigned short*)take(2 * 4 * 2 * 512 * 2);
    unsigned short* pWl4 = (unsigned short*)take(2 * 2 * 2 * 512 * 2);
    unsigned short* pWr4 = (unsigned short*)take(2 * 2 * 2 * 512 * 2);
    unsigned* pairs = (unsigned*)hA;   // aliases hA; consumed before layer-1 agg writes hA
    float* outf = (float*)d_out;

    hipMemsetAsync(bcnt8, 0, (size_t)8 * nbp * 4, stream);

    prepack_kernel<<<(2 * 4 * 4 * 512 + 255) / 256, 256, 0, stream>>>(Wl1, Wr1, pWl1, pWr1, 128, 64);
    prepack_kernel<<<(2 * 4 * 2 * 512 + 255) / 256, 256, 0, stream>>>(Wl2, Wr2, pWl2, pWr2, 64, 64);
    prepack_kernel<<<(2 * 4 * 2 * 512 + 255) / 256, 256, 0, stream>>>(Wl3, Wr3, pWl3, pWr3, 64, 64);
    prepack_kernel<<<(2 * 2 * 2 * 512 + 255) / 256, 256, 0, stream>>>(Wl4, Wr4, pWl4, pWr4, 64, 32);

    int kgrid = (E + CH - 1) / CH;
    bucket_hist<<<kgrid, 256, 0, stream>>>(dst, bcnt8, E, nb, nbp);
    bucket_scan<<<1, 1024, 0, stream>>>(bcnt8, bbase, bcur8, rowstart, nb, nbp, E, N);
    bucket_scatter<<<kgrid, 256, 0, stream>>>(src, dst, bcur8, pairs, E, nb, nbp);
    bucket_finalize<<<nb, 256, 0, stream>>>(pairs, bbase, rowstart, csr_src, N);

    int pblk = (N + 63) / 64;
    int agg64 = (N + 31) / 32;    // 4 waves/block, 8 nodes/wave
    int agg32 = (N + 63) / 64;    // 4 waves/block, 16 nodes/wave

    // layer 1: 128 -> 64, ELU
    proj_mfma_kernel<128, 64><<<pblk, 256, 0, stream>>>(x, pWl1, pWr1, att1, xlh, xrh, dl, dr, N);
    agg_kernel<64, 1><<<agg64, 256, 0, stream>>>(xlh, xrh, att1, dl, dr, rowstart, csr_src, hA, N, E);

    // layer 2: 64 -> 64, ELU
    proj_mfma_kernel<64, 64><<<pblk, 256, 0, stream>>>(hA, pWl2, pWr2, att2, xlh, xrh, dl, dr, N);
    agg_kernel<64, 1><<<agg64, 256, 0, stream>>>(xlh, xrh, att2, dl, dr, rowstart, csr_src, hB, N, E);

    // layer 3: 64 -> 64, ELU
    proj_mfma_kernel<64, 64><<<pblk, 256, 0, stream>>>(hB, pWl3, pWr3, att3, xlh, xrh, dl, dr, N);
    agg_kernel<64, 1><<<agg64, 256, 0, stream>>>(xlh, xrh, att3, dl, dr, rowstart, csr_src, hA, N, E);

    // layer 4: 64 -> 32, final ELU (alpha = 32)
    proj_mfma_kernel<64, 32><<<pblk, 256, 0, stream>>>(hA, pWl4, pWr4, att4, xlh, xrh, dl, dr, N);
    agg_kernel<32, 2><<<agg32, 256, 0, stream>>>(xlh, xrh, att4, dl, dr, rowstart, csr_src, outf, N, E);
}